// Round 1
// baseline (2491.144 us; speedup 1.0000x reference)
//
#include <hip/hip_runtime.h>
#include <float.h>

#define DD 256
#define D4 64            // DD/4
#define KK 8192
#define NROWS 32768
#define BM 64
#define BN 64
#define NELEM 8388608    // NROWS * DD

// ws layout (float units):
// [0, 32768)        z_norms
// [32768, 40960)    cb_norms
// [40960, 73728)    codes (int32)
// [73728, 81920)    loss partials (8192)

__global__ __launch_bounds__(256) void norms_kernel(
    const float* __restrict__ z, const float* __restrict__ cb,
    float* __restrict__ znorm, float* __restrict__ cbnorm)
{
    int wave = threadIdx.x >> 6;
    int lane = threadIdx.x & 63;
    int row = blockIdx.x * 4 + wave;
    const float4* src;
    float* dst;
    int r;
    if (row < NROWS) { src = (const float4*)z;  dst = znorm;  r = row; }
    else             { src = (const float4*)cb; dst = cbnorm; r = row - NROWS; }
    float4 v = src[(size_t)r * D4 + lane];
    float s = v.x*v.x + v.y*v.y + v.z*v.z + v.w*v.w;
    #pragma unroll
    for (int off = 1; off < 64; off <<= 1) s += __shfl_xor(s, off);
    if (lane == 0) dst[r] = s;
}

// Fused distance matmul + argmin. 64 rows x 8192 codes per block.
// LDS: zt 64KB (full z tile, d4-major) + cbt 16KB (cb chunk) = 80KB -> 2 blocks/CU.
__global__ __launch_bounds__(256, 2) void vq_argmin_kernel(
    const float* __restrict__ z, const float* __restrict__ cb,
    const float* __restrict__ znorm, const float* __restrict__ cbnorm,
    int* __restrict__ codes, float* __restrict__ codes_f)
{
    __shared__ float4 zt[D4][BM];    // [d4][row]  64*64*16B = 64KB
    __shared__ float4 cbt[16][BN];   // [d4-in-chunk][k] 16KB
    const int tid = threadIdx.x;
    const int tx = tid & 15;         // code group
    const int ty = tid >> 4;         // row group
    const int rowBase = blockIdx.x * BM;
    const float4* zf4 = (const float4*)z;
    const float4* cf4 = (const float4*)cb;

    // stage z tile once: rows rowBase..+63, all 256 d (coalesced global reads)
    #pragma unroll
    for (int i = 0; i < 16; ++i) {
        int lid = i * 256 + tid;
        int d4 = lid & 63;
        int r  = lid >> 6;
        zt[d4][r] = zf4[(size_t)(rowBase + r) * D4 + d4];
    }

    float zn[4], bestd[4];
    int bestk[4];
    #pragma unroll
    for (int r = 0; r < 4; ++r) {
        zn[r] = znorm[rowBase + ty + 16 * r];
        bestd[r] = FLT_MAX;
        bestk[r] = 0;
    }
    __syncthreads();

    for (int kt = 0; kt < KK / BN; ++kt) {
        float acc[4][4];
        #pragma unroll
        for (int r = 0; r < 4; ++r)
            #pragma unroll
            for (int c = 0; c < 4; ++c) acc[r][c] = 0.f;

        for (int dc = 0; dc < 4; ++dc) {
            // stage cb chunk: 64 codes x 64 d (16 float4)
            #pragma unroll
            for (int i = 0; i < 4; ++i) {
                int lid = i * 256 + tid;
                int d4 = lid & 15;
                int k  = lid >> 4;
                cbt[d4][k] = cf4[(size_t)(kt * BN + k) * D4 + dc * 16 + d4];
            }
            __syncthreads();
            #pragma unroll 4
            for (int d4 = 0; d4 < 16; ++d4) {
                float4 zfr[4], cfr[4];
                #pragma unroll
                for (int r = 0; r < 4; ++r) zfr[r] = zt[dc * 16 + d4][ty + 16 * r];
                #pragma unroll
                for (int c = 0; c < 4; ++c) cfr[c] = cbt[d4][tx + 16 * c];
                #pragma unroll
                for (int r = 0; r < 4; ++r)
                    #pragma unroll
                    for (int c = 0; c < 4; ++c) {
                        acc[r][c] = fmaf(zfr[r].x, cfr[c].x, acc[r][c]);
                        acc[r][c] = fmaf(zfr[r].y, cfr[c].y, acc[r][c]);
                        acc[r][c] = fmaf(zfr[r].z, cfr[c].z, acc[r][c]);
                        acc[r][c] = fmaf(zfr[r].w, cfr[c].w, acc[r][c]);
                    }
            }
            __syncthreads();
        }
        // dist = (zn - 2*dot) + cbn, exactly matching reference combine order.
        // Iterate c ascending => k ascending within thread; strict < keeps lowest k.
        #pragma unroll
        for (int c = 0; c < 4; ++c) {
            int k = kt * BN + tx + 16 * c;
            float cn = cbnorm[k];
            #pragma unroll
            for (int r = 0; r < 4; ++r) {
                float dist = fmaf(-2.f, acc[r][c], zn[r]) + cn;
                if (dist < bestd[r]) { bestd[r] = dist; bestk[r] = k; }
            }
        }
    }

    // lexicographic-(dist,k) min across the 16 tx lanes of each row
    #pragma unroll
    for (int off = 1; off < 16; off <<= 1) {
        #pragma unroll
        for (int r = 0; r < 4; ++r) {
            float od = __shfl_xor(bestd[r], off);
            int   ok = __shfl_xor(bestk[r], off);
            if (od < bestd[r] || (od == bestd[r] && ok < bestk[r])) {
                bestd[r] = od; bestk[r] = ok;
            }
        }
    }
    if (tx == 0) {
        #pragma unroll
        for (int r = 0; r < 4; ++r) {
            int row = rowBase + ty + 16 * r;
            codes[row] = bestk[r];
            codes_f[row] = (float)bestk[r];
        }
    }
}

// z_q gather + straight-through output + deterministic loss partials.
// 256 threads * 1 float4 = 1024 floats = 4 rows per block.
__global__ __launch_bounds__(256) void gather_loss_kernel(
    const float* __restrict__ z, const float* __restrict__ cb,
    const int* __restrict__ codes, float* __restrict__ zq_out,
    float* __restrict__ partials)
{
    __shared__ float red[4];
    int tid = threadIdx.x;
    size_t e4 = (size_t)blockIdx.x * 256 + tid;  // float4 index
    int row = (int)(e4 >> 6);
    int d4  = (int)(e4 & 63);
    int code = codes[row];
    float4 q  = ((const float4*)cb)[(size_t)code * D4 + d4];
    float4 zv = ((const float4*)z)[e4];
    // z_q_st = z + (z_q - z): reproduce the reference's fp32 rounding exactly
    float dx = q.x - zv.x, dy = q.y - zv.y, dz = q.z - zv.z, dw = q.w - zv.w;
    float4 o;
    o.x = zv.x + dx; o.y = zv.y + dy; o.z = zv.z + dz; o.w = zv.w + dw;
    ((float4*)zq_out)[e4] = o;
    float s = dx*dx + dy*dy + dz*dz + dw*dw;
    #pragma unroll
    for (int off = 1; off < 64; off <<= 1) s += __shfl_xor(s, off);
    if ((tid & 63) == 0) red[tid >> 6] = s;
    __syncthreads();
    if (tid == 0) partials[blockIdx.x] = ((red[0] + red[1]) + red[2]) + red[3];
}

__global__ __launch_bounds__(256) void final_loss_kernel(
    const float* __restrict__ partials, float* __restrict__ out_loss)
{
    __shared__ float red[4];
    int tid = threadIdx.x;
    float s = 0.f;
    #pragma unroll 4
    for (int i = 0; i < 32; ++i) s += partials[tid * 32 + i];
    #pragma unroll
    for (int off = 1; off < 64; off <<= 1) s += __shfl_xor(s, off);
    if ((tid & 63) == 0) red[tid >> 6] = s;
    __syncthreads();
    if (tid == 0) {
        float tot = ((red[0] + red[1]) + red[2]) + red[3];
        // total_loss = 0.25*mean + 0.25*mean = 0.5*mean(diff^2)
        out_loss[0] = 0.5f * (tot / (float)NELEM);
    }
}

extern "C" void kernel_launch(void* const* d_in, const int* in_sizes, int n_in,
                              void* d_out, int out_size, void* d_ws, size_t ws_size,
                              hipStream_t stream) {
    const float* z  = (const float*)d_in[0];
    const float* cb = (const float*)d_in[1];
    float* out      = (float*)d_out;
    float* zq_out   = out;                 // [0, 8388608)
    float* loss_out = out + NELEM;         // [8388608]
    float* codes_f  = out + NELEM + 1;     // [8388609, 8421377)

    float* ws       = (float*)d_ws;
    float* znorm    = ws;                  // 32768
    float* cbnorm   = ws + 32768;          // 8192
    int*   codes    = (int*)(ws + 40960);  // 32768 ints
    float* partials = ws + 73728;          // 8192

    norms_kernel<<<10240, 256, 0, stream>>>(z, cb, znorm, cbnorm);
    vq_argmin_kernel<<<512, 256, 0, stream>>>(z, cb, znorm, cbnorm, codes, codes_f);
    gather_loss_kernel<<<8192, 256, 0, stream>>>(z, cb, codes, zq_out, partials);
    final_loss_kernel<<<1, 256, 0, stream>>>(partials, loss_out);
}

// Round 4
// 1910.752 us; speedup vs baseline: 1.3038x; 1.3038x over previous
//
#include <hip/hip_runtime.h>
#include <hip/hip_fp16.h>
#include <float.h>

typedef _Float16 half8 __attribute__((ext_vector_type(8)));
typedef _Float16 half4 __attribute__((ext_vector_type(4)));
typedef float floatx4 __attribute__((ext_vector_type(4)));

#define DD 256
#define D4 64            // DD/4
#define KK 8192
#define NROWS 32768
#define BM 128           // rows per block
#define BKT 256          // codes per kt step (4 col-groups * 64)
#define NELEM 8388608    // NROWS * DD
#define TAU 2e-3f        // refine margin: ~50x worst-case fp16-path dist error

// ws layout (bytes):
// 0        znorm   (32768 f)
// 131072   cbnorm  (8192 f)
// 163840   codes   (32768 i32)
// 294912   partials(8192 f)
// 327680   cnt     (i32)
// 327696   list    (32768 i32)  -> ends 458768
// 460800   bhi     (fp16 hi plane of 16*cb, 4MB)
// 4655104  blo     (fp16 lo plane *2^11, 4MB) -> ends 8849408
#define WS_REFINE_BYTES 458768
#define WS_FULL_BYTES   8849408

__global__ __launch_bounds__(256) void norms_kernel(
    const float* __restrict__ z, const float* __restrict__ cb,
    float* __restrict__ znorm, float* __restrict__ cbnorm)
{
    int wave = threadIdx.x >> 6;
    int lane = threadIdx.x & 63;
    int row = blockIdx.x * 4 + wave;
    const float4* src;
    float* dst;
    int r;
    if (row < NROWS) { src = (const float4*)z;  dst = znorm;  r = row; }
    else             { src = (const float4*)cb; dst = cbnorm; r = row - NROWS; }
    float4 v = src[(size_t)r * D4 + lane];
    float s = v.x*v.x + v.y*v.y + v.z*v.z + v.w*v.w;
    #pragma unroll
    for (int off = 1; off < 64; off <<= 1) s += __shfl_xor(s, off);
    if (lane == 0) dst[r] = s;
}

__global__ __launch_bounds__(256) void preconv_kernel(
    const float* __restrict__ cb, _Float16* __restrict__ bhi, _Float16* __restrict__ blo)
{
    size_t e4 = (size_t)blockIdx.x * 256 + threadIdx.x;
    float4 v = ((const float4*)cb)[e4];
    float t0 = v.x * 16.f, t1 = v.y * 16.f, t2 = v.z * 16.f, t3 = v.w * 16.f;
    _Float16 h0 = (_Float16)t0, h1 = (_Float16)t1, h2 = (_Float16)t2, h3 = (_Float16)t3;
    _Float16 l0 = (_Float16)((t0 - (float)h0) * 2048.f);
    _Float16 l1 = (_Float16)((t1 - (float)h1) * 2048.f);
    _Float16 l2 = (_Float16)((t2 - (float)h2) * 2048.f);
    _Float16 l3 = (_Float16)((t3 - (float)h3) * 2048.f);
    reinterpret_cast<half4*>(bhi)[e4] = half4{h0, h1, h2, h3};
    reinterpret_cast<half4*>(blo)[e4] = half4{l0, l1, l2, l3};
}

// MFMA distance + argmin with top-2 margin tracking.
// 128 rows x 8192 codes per block, 8 waves (2 rg x 4 cg), cross-cg LDS reduce.
template <bool PRECONV, bool REFINE>
__global__ __launch_bounds__(512, 1) void vq_mfma_kernel(
    const float* __restrict__ z, const float* __restrict__ cb,
    const _Float16* __restrict__ bhip, const _Float16* __restrict__ blop,
    const float* __restrict__ znorm, const float* __restrict__ cbnorm,
    int* __restrict__ codes, float* __restrict__ codes_f,
    int* __restrict__ cnt, int* __restrict__ list)
{
    __shared__ _Float16 zhi[BM * DD];   // 64 KB, swizzled 16B groups
    __shared__ _Float16 zlo[BM * DD];   // 64 KB

    const int tid  = threadIdx.x;
    const int lane = tid & 63;
    const int w    = tid >> 6;       // wave 0..7
    const int rg   = w >> 2;         // row group 0..1 (64 rows each)
    const int cg   = w & 3;          // col group 0..3 (64 codes each per kt)
    const int l15  = lane & 15;
    const int lhi  = lane >> 4;      // 0..3
    const int rowBase = blockIdx.x * BM;

    // ---- stage z -> hi/lo fp16 LDS (lo scaled 2^11), swizzle g ^= (row&7) ----
    #pragma unroll
    for (int i = 0; i < 16; ++i) {
        int gid = i * 512 + tid;
        int r   = gid >> 6;
        int c4  = gid & 63;
        float4 v = ((const float4*)z)[(size_t)(rowBase + r) * D4 + c4];
        _Float16 h0 = (_Float16)v.x, h1 = (_Float16)v.y,
                 h2 = (_Float16)v.z, h3 = (_Float16)v.w;
        _Float16 e0 = (_Float16)((v.x - (float)h0) * 2048.f);
        _Float16 e1 = (_Float16)((v.y - (float)h1) * 2048.f);
        _Float16 e2 = (_Float16)((v.z - (float)h2) * 2048.f);
        _Float16 e3 = (_Float16)((v.w - (float)h3) * 2048.f);
        int g = c4 >> 1;
        int byteOff = r * 512 + (((g ^ (r & 7))) << 4) + ((c4 & 1) << 3);
        *reinterpret_cast<half4*>(reinterpret_cast<char*>(zhi) + byteOff) = half4{h0, h1, h2, h3};
        *reinterpret_cast<half4*>(reinterpret_cast<char*>(zlo) + byteOff) = half4{e0, e1, e2, e3};
    }

    int rowA[4];
    #pragma unroll
    for (int rf = 0; rf < 4; ++rf) rowA[rf] = rg * 64 + rf * 16 + l15;

    float zn[4][4];
    #pragma unroll
    for (int rf = 0; rf < 4; ++rf)
        #pragma unroll
        for (int reg = 0; reg < 4; ++reg)
            zn[rf][reg] = znorm[rowBase + rg * 64 + rf * 16 + lhi * 4 + reg];

    float bestd[4][4], secd[4][4];
    int   bestk[4][4];
    #pragma unroll
    for (int rf = 0; rf < 4; ++rf)
        #pragma unroll
        for (int reg = 0; reg < 4; ++reg) {
            bestd[rf][reg] = FLT_MAX; secd[rf][reg] = FLT_MAX; bestk[rf][reg] = 0;
        }

    __syncthreads();

    for (int kt = 0; kt < KK / BKT; ++kt) {
        floatx4 accH[4][4], accM[4][4];
        #pragma unroll
        for (int rf = 0; rf < 4; ++rf)
            #pragma unroll
            for (int cf = 0; cf < 4; ++cf) {
                accH[rf][cf] = floatx4{0.f, 0.f, 0.f, 0.f};
                accM[rf][cf] = floatx4{0.f, 0.f, 0.f, 0.f};
            }

        const int codeBase = kt * BKT + cg * 64 + l15;

        for (int dc = 0; dc < 8; ++dc) {
            half8 bhi_f[4], blo_f[4];
            #pragma unroll
            for (int cf = 0; cf < 4; ++cf) {
                if (PRECONV) {
                    size_t off = (size_t)(codeBase + 16 * cf) * DD + dc * 32 + lhi * 8;
                    bhi_f[cf] = *reinterpret_cast<const half8*>(bhip + off);
                    blo_f[cf] = *reinterpret_cast<const half8*>(blop + off);
                } else {
                    const float4* p = (const float4*)(cb + (size_t)(codeBase + 16 * cf) * DD + dc * 32 + lhi * 8);
                    float4 u0 = p[0];
                    float4 u1 = p[1];
                    float uv[8] = {u0.x, u0.y, u0.z, u0.w, u1.x, u1.y, u1.z, u1.w};
                    half8 bh, bl;
                    #pragma unroll
                    for (int j = 0; j < 8; ++j) {
                        float t = uv[j] * 16.f;
                        _Float16 h = (_Float16)t;
                        bh[j] = h;
                        bl[j] = (_Float16)((t - (float)h) * 2048.f);
                    }
                    bhi_f[cf] = bh; blo_f[cf] = bl;
                }
            }
            #pragma unroll
            for (int rf = 0; rf < 4; ++rf) {
                int g = dc * 4 + lhi;
                int off = rowA[rf] * 512 + ((g ^ (rowA[rf] & 7)) << 4);
                half8 ahi = *reinterpret_cast<const half8*>(reinterpret_cast<const char*>(zhi) + off);
                half8 alo = *reinterpret_cast<const half8*>(reinterpret_cast<const char*>(zlo) + off);
                #pragma unroll
                for (int cf = 0; cf < 4; ++cf) {
                    accH[rf][cf] = __builtin_amdgcn_mfma_f32_16x16x32_f16(ahi, bhi_f[cf], accH[rf][cf], 0, 0, 0);
                    accM[rf][cf] = __builtin_amdgcn_mfma_f32_16x16x32_f16(alo, bhi_f[cf], accM[rf][cf], 0, 0, 0);
                    accM[rf][cf] = __builtin_amdgcn_mfma_f32_16x16x32_f16(ahi, blo_f[cf], accM[rf][cf], 0, 0, 0);
                }
            }
        }

        // dist = (zn - 2*dot) + cbn with reference-equivalent rounding; track top-2
        #pragma unroll
        for (int cf = 0; cf < 4; ++cf) {
            int k = codeBase + 16 * cf;
            float cn = cbnorm[k];
            #pragma unroll
            for (int rf = 0; rf < 4; ++rf)
                #pragma unroll
                for (int reg = 0; reg < 4; ++reg) {
                    float dot16 = fmaf(accM[rf][cf][reg], 0x1p-11f, accH[rf][cf][reg]);
                    float dist  = fmaf(-0.125f, dot16, zn[rf][reg]) + cn;
                    if (dist < bestd[rf][reg]) {
                        secd[rf][reg] = bestd[rf][reg];
                        bestd[rf][reg] = dist; bestk[rf][reg] = k;
                    } else {
                        secd[rf][reg] = fminf(secd[rf][reg], dist);
                    }
                }
        }
    }

    // reduce across the 16 code-lanes, lexicographic (d,k), carrying second-best
    #pragma unroll
    for (int off = 1; off < 16; off <<= 1) {
        #pragma unroll
        for (int rf = 0; rf < 4; ++rf)
            #pragma unroll
            for (int reg = 0; reg < 4; ++reg) {
                float od = __shfl_xor(bestd[rf][reg], off);
                int   ok = __shfl_xor(bestk[rf][reg], off);
                float os = __shfl_xor(secd[rf][reg], off);
                float hi = fmaxf(bestd[rf][reg], od);
                secd[rf][reg] = fminf(fminf(secd[rf][reg], os), hi);
                if (od < bestd[rf][reg] || (od == bestd[rf][reg] && ok < bestk[rf][reg])) {
                    bestd[rf][reg] = od; bestk[rf][reg] = ok;
                }
            }
    }

    // cross-cg reduction via LDS scratch (reuse zhi)
    __syncthreads();
    float* dsc = reinterpret_cast<float*>(zhi);          // [4][128]
    int*   ksc = reinterpret_cast<int*>(zhi) + 512;      // [4][128]
    float* ssc = reinterpret_cast<float*>(zhi) + 1024;   // [4][128]
    if (l15 == 0) {
        #pragma unroll
        for (int rf = 0; rf < 4; ++rf)
            #pragma unroll
            for (int reg = 0; reg < 4; ++reg) {
                int rrow = rg * 64 + rf * 16 + lhi * 4 + reg;
                dsc[cg * 128 + rrow] = bestd[rf][reg];
                ksc[cg * 128 + rrow] = bestk[rf][reg];
                ssc[cg * 128 + rrow] = secd[rf][reg];
            }
    }
    __syncthreads();
    if (tid < 128) {
        float bd = dsc[tid];
        int   bk = ksc[tid];
        float sd = ssc[tid];
        #pragma unroll
        for (int c = 1; c < 4; ++c) {
            float od = dsc[c * 128 + tid];
            int   ok = ksc[c * 128 + tid];
            float os = ssc[c * 128 + tid];
            float hi = fmaxf(bd, od);
            sd = fminf(fminf(sd, os), hi);
            if (od < bd || (od == bd && ok < bk)) { bd = od; bk = ok; }
        }
        int row = rowBase + tid;
        codes[row]   = bk;
        codes_f[row] = (float)bk;
        if (REFINE && (sd - bd) < TAU) {
            int idx = atomicAdd(cnt, 1);
            list[idx] = row;
        }
    }
}

// Full fp32 re-argmin for flagged (near-tie) rows. One block per list entry.
__global__ __launch_bounds__(256) void refine_kernel(
    const float* __restrict__ z, const float* __restrict__ cb,
    const float* __restrict__ znorm, const float* __restrict__ cbnorm,
    const int* __restrict__ cnt, const int* __restrict__ list,
    int* __restrict__ codes, float* __restrict__ codes_f)
{
    __shared__ float zrow[DD];
    __shared__ float dred[4];
    __shared__ int   kred[4];
    const int tid = threadIdx.x;
    const int lane = tid & 63;
    const int wv = tid >> 6;
    const int n = *cnt;
    for (int i = blockIdx.x; i < n; i += gridDim.x) {
        const int row = list[i];
        if (tid < 64) ((float4*)zrow)[tid] = ((const float4*)z)[(size_t)row * D4 + tid];
        const float zn = znorm[row];
        __syncthreads();
        float bd = FLT_MAX;
        int   bk = 0;
        for (int k = tid; k < KK; k += 256) {
            const float4* crow = (const float4*)cb + (size_t)k * D4;
            float acc = 0.f;
            #pragma unroll 8
            for (int d4 = 0; d4 < D4; ++d4) {
                float4 c = crow[d4];
                float4 zv = ((const float4*)zrow)[d4];
                acc = fmaf(zv.x, c.x, acc);
                acc = fmaf(zv.y, c.y, acc);
                acc = fmaf(zv.z, c.z, acc);
                acc = fmaf(zv.w, c.w, acc);
            }
            float dist = fmaf(-2.f, acc, zn) + cbnorm[k];
            if (dist < bd) { bd = dist; bk = k; }
        }
        #pragma unroll
        for (int off = 1; off < 64; off <<= 1) {
            float od = __shfl_xor(bd, off);
            int   ok = __shfl_xor(bk, off);
            if (od < bd || (od == bd && ok < bk)) { bd = od; bk = ok; }
        }
        if (lane == 0) { dred[wv] = bd; kred[wv] = bk; }
        __syncthreads();
        if (tid == 0) {
            #pragma unroll
            for (int c = 1; c < 4; ++c) {
                if (dred[c] < bd || (dred[c] == bd && kred[c] < bk)) { bd = dred[c]; bk = kred[c]; }
            }
            codes[row]   = bk;
            codes_f[row] = (float)bk;
        }
        __syncthreads();
    }
}

__global__ __launch_bounds__(256) void gather_loss_kernel(
    const float* __restrict__ z, const float* __restrict__ cb,
    const int* __restrict__ codes, float* __restrict__ zq_out,
    float* __restrict__ partials)
{
    __shared__ float red[4];
    int tid = threadIdx.x;
    size_t e4 = (size_t)blockIdx.x * 256 + tid;
    int row = (int)(e4 >> 6);
    int d4  = (int)(e4 & 63);
    int code = codes[row];
    float4 q  = ((const float4*)cb)[(size_t)code * D4 + d4];
    float4 zv = ((const float4*)z)[e4];
    float dx = q.x - zv.x, dy = q.y - zv.y, dz = q.z - zv.z, dw = q.w - zv.w;
    float4 o;
    o.x = zv.x + dx; o.y = zv.y + dy; o.z = zv.z + dz; o.w = zv.w + dw;
    ((float4*)zq_out)[e4] = o;
    float s = dx*dx + dy*dy + dz*dz + dw*dw;
    #pragma unroll
    for (int off = 1; off < 64; off <<= 1) s += __shfl_xor(s, off);
    if ((tid & 63) == 0) red[tid >> 6] = s;
    __syncthreads();
    if (tid == 0) partials[blockIdx.x] = ((red[0] + red[1]) + red[2]) + red[3];
}

__global__ __launch_bounds__(256) void final_loss_kernel(
    const float* __restrict__ partials, float* __restrict__ out_loss)
{
    __shared__ float red[4];
    int tid = threadIdx.x;
    float s = 0.f;
    #pragma unroll 4
    for (int i = 0; i < 32; ++i) s += partials[tid * 32 + i];
    #pragma unroll
    for (int off = 1; off < 64; off <<= 1) s += __shfl_xor(s, off);
    if ((tid & 63) == 0) red[tid >> 6] = s;
    __syncthreads();
    if (tid == 0) {
        float tot = ((red[0] + red[1]) + red[2]) + red[3];
        out_loss[0] = 0.5f * (tot / (float)NELEM);
    }
}

extern "C" void kernel_launch(void* const* d_in, const int* in_sizes, int n_in,
                              void* d_out, int out_size, void* d_ws, size_t ws_size,
                              hipStream_t stream) {
    const float* z  = (const float*)d_in[0];
    const float* cb = (const float*)d_in[1];
    float* out      = (float*)d_out;
    float* zq_out   = out;
    float* loss_out = out + NELEM;
    float* codes_f  = out + NELEM + 1;

    char* wsb       = (char*)d_ws;
    float* znorm    = (float*)(wsb + 0);
    float* cbnorm   = (float*)(wsb + 131072);
    int*   codes    = (int*)(wsb + 163840);
    float* partials = (float*)(wsb + 294912);
    int*   cnt      = (int*)(wsb + 327680);
    int*   list     = (int*)(wsb + 327696);
    _Float16* bhi   = (_Float16*)(wsb + 460800);
    _Float16* blo   = (_Float16*)(wsb + 4655104);

    const bool preconv = ws_size >= (size_t)WS_FULL_BYTES;
    const bool refine  = ws_size >= (size_t)WS_REFINE_BYTES;

    norms_kernel<<<10240, 256, 0, stream>>>(z, cb, znorm, cbnorm);
    if (refine) hipMemsetAsync(cnt, 0, sizeof(int), stream);
    if (preconv) preconv_kernel<<<2048, 256, 0, stream>>>(cb, bhi, blo);

    if (preconv && refine)
        vq_mfma_kernel<true, true><<<NROWS / BM, 512, 0, stream>>>(z, cb, bhi, blo, znorm, cbnorm, codes, codes_f, cnt, list);
    else if (preconv)
        vq_mfma_kernel<true, false><<<NROWS / BM, 512, 0, stream>>>(z, cb, bhi, blo, znorm, cbnorm, codes, codes_f, cnt, list);
    else if (refine)
        vq_mfma_kernel<false, true><<<NROWS / BM, 512, 0, stream>>>(z, cb, bhi, blo, znorm, cbnorm, codes, codes_f, cnt, list);
    else
        vq_mfma_kernel<false, false><<<NROWS / BM, 512, 0, stream>>>(z, cb, bhi, blo, znorm, cbnorm, codes, codes_f, cnt, list);

    if (refine)
        refine_kernel<<<256, 256, 0, stream>>>(z, cb, znorm, cbnorm, cnt, list, codes, codes_f);

    gather_loss_kernel<<<8192, 256, 0, stream>>>(z, cb, codes, zq_out, partials);
    final_loss_kernel<<<1, 256, 0, stream>>>(partials, loss_out);
}

// Round 5
// 928.349 us; speedup vs baseline: 2.6834x; 2.0582x over previous
//
#include <hip/hip_runtime.h>
#include <hip/hip_fp16.h>
#include <float.h>

typedef _Float16 half8 __attribute__((ext_vector_type(8)));
typedef _Float16 half4 __attribute__((ext_vector_type(4)));
typedef float floatx4 __attribute__((ext_vector_type(4)));

#define DD 256
#define D4 64            // DD/4
#define KK 8192
#define NROWS 32768
#define BM 128           // rows per tile
#define NELEM 8388608    // NROWS * DD
#define TAU 2e-3f        // refine margin
#define NSLICE 8
#define SLICE_K 1024     // KK / NSLICE
#define NTILES 256       // NROWS / BM
#define TILES_PER_BLOCK 8

// ---- sliced ws layout (bytes) ----
// 0        znorm   (32768 f)
// 131072   cbnorm  (8192 f)
// 163840   codes   (32768 i32)
// 294912   loss partials (8192 f)
// 327680   cnt     (i32)
// 327696   list    (32768 i32)          -> 458768
// 460800   pd      (32768*8 f, 1MB)     -> 1509376
// 1509376  ps      (1MB)                -> 2557952
// 2557952  pk      (1MB i32)            -> 3606528
// 3606528  bhi     (fp16[KK*DD], 4MB)   -> 7800832
// 7800832  blo     (4MB)                -> 11995136
#define WS_SLICED_BYTES 11995136
// ---- round-4 fallback layout ----
#define WS_R4_REFINE_BYTES 458768
#define WS_R4_FULL_BYTES   8849408

__global__ __launch_bounds__(256) void norms_kernel(
    const float* __restrict__ z, const float* __restrict__ cb,
    float* __restrict__ znorm, float* __restrict__ cbnorm)
{
    int wave = threadIdx.x >> 6;
    int lane = threadIdx.x & 63;
    int row = blockIdx.x * 4 + wave;
    const float4* src;
    float* dst;
    int r;
    if (row < NROWS) { src = (const float4*)z;  dst = znorm;  r = row; }
    else             { src = (const float4*)cb; dst = cbnorm; r = row - NROWS; }
    float4 v = src[(size_t)r * D4 + lane];
    float s = v.x*v.x + v.y*v.y + v.z*v.z + v.w*v.w;
    #pragma unroll
    for (int off = 1; off < 64; off <<= 1) s += __shfl_xor(s, off);
    if (lane == 0) dst[r] = s;
}

__global__ __launch_bounds__(256) void preconv_kernel(
    const float* __restrict__ cb, _Float16* __restrict__ bhi, _Float16* __restrict__ blo)
{
    size_t e4 = (size_t)blockIdx.x * 256 + threadIdx.x;
    float4 v = ((const float4*)cb)[e4];
    float t0 = v.x * 16.f, t1 = v.y * 16.f, t2 = v.z * 16.f, t3 = v.w * 16.f;
    _Float16 h0 = (_Float16)t0, h1 = (_Float16)t1, h2 = (_Float16)t2, h3 = (_Float16)t3;
    _Float16 l0 = (_Float16)((t0 - (float)h0) * 2048.f);
    _Float16 l1 = (_Float16)((t1 - (float)h1) * 2048.f);
    _Float16 l2 = (_Float16)((t2 - (float)h2) * 2048.f);
    _Float16 l3 = (_Float16)((t3 - (float)h3) * 2048.f);
    reinterpret_cast<half4*>(bhi)[e4] = half4{h0, h1, h2, h3};
    reinterpret_cast<half4*>(blo)[e4] = half4{l0, l1, l2, l3};
}

// ---------------- XCD-sliced MFMA kernel ----------------
// 256 blocks (co-resident, 1/CU). slice = blockIdx&7 (= XCD via round-robin):
// each XCD's 32 blocks re-read the SAME 1MB B-slice -> L2-resident.
// Each block: 8 row-tiles of 128 rows vs its 1024-code slice.
// 8 waves = 2 rg x 4 cg; per-wave tile rf=4 (64 rows) x cf=2 (32 codes/kt).
__global__ __launch_bounds__(512, 2) void vq_sliced_kernel(
    const float* __restrict__ z,
    const _Float16* __restrict__ bhip, const _Float16* __restrict__ blop,
    const float* __restrict__ znorm, const float* __restrict__ cbnorm,
    float* __restrict__ pd, float* __restrict__ ps, int* __restrict__ pk)
{
    __shared__ _Float16 zhi[BM * DD];   // 64 KB, swizzled 16B groups
    __shared__ _Float16 zlo[BM * DD];   // 64 KB

    const int tid  = threadIdx.x;
    const int lane = tid & 63;
    const int w    = tid >> 6;
    const int rg   = w >> 2;         // 0..1
    const int cg   = w & 3;          // 0..3
    const int l15  = lane & 15;
    const int lhi  = lane >> 4;      // 0..3
    const int slice = blockIdx.x & 7;
    const int grp   = blockIdx.x >> 3;       // 0..31
    const int sliceBase = slice * SLICE_K;

    int rowA[4];
    #pragma unroll
    for (int rf = 0; rf < 4; ++rf) rowA[rf] = rg * 64 + rf * 16 + l15;

    #pragma unroll 1
    for (int j = 0; j < TILES_PER_BLOCK; ++j) {
        const int rowBase = (grp * TILES_PER_BLOCK + j) * BM;

        __syncthreads();   // previous iter's LDS reads (scratch) done
        // ---- stage z tile -> hi/lo fp16 LDS (lo*2^11), swizzle g ^= (row&7) ----
        #pragma unroll
        for (int i = 0; i < 16; ++i) {
            int gid = i * 512 + tid;
            int r   = gid >> 6;
            int c4  = gid & 63;
            float4 v = ((const float4*)z)[(size_t)(rowBase + r) * D4 + c4];
            _Float16 h0 = (_Float16)v.x, h1 = (_Float16)v.y,
                     h2 = (_Float16)v.z, h3 = (_Float16)v.w;
            _Float16 e0 = (_Float16)((v.x - (float)h0) * 2048.f);
            _Float16 e1 = (_Float16)((v.y - (float)h1) * 2048.f);
            _Float16 e2 = (_Float16)((v.z - (float)h2) * 2048.f);
            _Float16 e3 = (_Float16)((v.w - (float)h3) * 2048.f);
            int g = c4 >> 1;
            int byteOff = r * 512 + (((g ^ (r & 7))) << 4) + ((c4 & 1) << 3);
            *reinterpret_cast<half4*>(reinterpret_cast<char*>(zhi) + byteOff) = half4{h0, h1, h2, h3};
            *reinterpret_cast<half4*>(reinterpret_cast<char*>(zlo) + byteOff) = half4{e0, e1, e2, e3};
        }

        float zn[4][4];
        #pragma unroll
        for (int rf = 0; rf < 4; ++rf)
            #pragma unroll
            for (int reg = 0; reg < 4; ++reg)
                zn[rf][reg] = znorm[rowBase + rg * 64 + rf * 16 + lhi * 4 + reg];

        float bestd[4][4], secd[4][4];
        int   bestk[4][4];
        #pragma unroll
        for (int rf = 0; rf < 4; ++rf)
            #pragma unroll
            for (int reg = 0; reg < 4; ++reg) {
                bestd[rf][reg] = FLT_MAX; secd[rf][reg] = FLT_MAX; bestk[rf][reg] = 0;
            }

        __syncthreads();

        #pragma unroll 1
        for (int kt = 0; kt < SLICE_K / 128; ++kt) {   // 8 steps of 128 codes
            floatx4 accH[4][2], accM[4][2];
            #pragma unroll
            for (int rf = 0; rf < 4; ++rf)
                #pragma unroll
                for (int cf = 0; cf < 2; ++cf) {
                    accH[rf][cf] = floatx4{0.f, 0.f, 0.f, 0.f};
                    accM[rf][cf] = floatx4{0.f, 0.f, 0.f, 0.f};
                }

            const int codeBase = sliceBase + kt * 128 + cg * 32 + l15;

            #pragma unroll 2
            for (int dc = 0; dc < 8; ++dc) {
                half8 bhi_f[2], blo_f[2];
                #pragma unroll
                for (int cf = 0; cf < 2; ++cf) {
                    size_t off = (size_t)(codeBase + 16 * cf) * DD + dc * 32 + lhi * 8;
                    bhi_f[cf] = *reinterpret_cast<const half8*>(bhip + off);
                    blo_f[cf] = *reinterpret_cast<const half8*>(blop + off);
                }
                #pragma unroll
                for (int rf = 0; rf < 4; ++rf) {
                    int g = dc * 4 + lhi;
                    int off = rowA[rf] * 512 + ((g ^ (rowA[rf] & 7)) << 4);
                    half8 ahi = *reinterpret_cast<const half8*>(reinterpret_cast<const char*>(zhi) + off);
                    half8 alo = *reinterpret_cast<const half8*>(reinterpret_cast<const char*>(zlo) + off);
                    #pragma unroll
                    for (int cf = 0; cf < 2; ++cf) {
                        accH[rf][cf] = __builtin_amdgcn_mfma_f32_16x16x32_f16(ahi, bhi_f[cf], accH[rf][cf], 0, 0, 0);
                        accM[rf][cf] = __builtin_amdgcn_mfma_f32_16x16x32_f16(alo, bhi_f[cf], accM[rf][cf], 0, 0, 0);
                        accM[rf][cf] = __builtin_amdgcn_mfma_f32_16x16x32_f16(ahi, blo_f[cf], accM[rf][cf], 0, 0, 0);
                    }
                }
            }

            // dist = (zn - 2*dot) + cbn, reference-equivalent rounding; track top-2
            #pragma unroll
            for (int cf = 0; cf < 2; ++cf) {
                int k = codeBase + 16 * cf;
                float cn = cbnorm[k];
                #pragma unroll
                for (int rf = 0; rf < 4; ++rf)
                    #pragma unroll
                    for (int reg = 0; reg < 4; ++reg) {
                        float dot16 = fmaf(accM[rf][cf][reg], 0x1p-11f, accH[rf][cf][reg]);
                        float dist  = fmaf(-0.125f, dot16, zn[rf][reg]) + cn;
                        if (dist < bestd[rf][reg]) {
                            secd[rf][reg] = bestd[rf][reg];
                            bestd[rf][reg] = dist; bestk[rf][reg] = k;
                        } else {
                            secd[rf][reg] = fminf(secd[rf][reg], dist);
                        }
                    }
            }
        }

        // reduce across 16 code-lanes, lexicographic (d,k), carrying second-best
        #pragma unroll
        for (int off = 1; off < 16; off <<= 1) {
            #pragma unroll
            for (int rf = 0; rf < 4; ++rf)
                #pragma unroll
                for (int reg = 0; reg < 4; ++reg) {
                    float od = __shfl_xor(bestd[rf][reg], off);
                    int   ok = __shfl_xor(bestk[rf][reg], off);
                    float os = __shfl_xor(secd[rf][reg], off);
                    float hi = fmaxf(bestd[rf][reg], od);
                    secd[rf][reg] = fminf(fminf(secd[rf][reg], os), hi);
                    if (od < bestd[rf][reg] || (od == bestd[rf][reg] && ok < bestk[rf][reg])) {
                        bestd[rf][reg] = od; bestk[rf][reg] = ok;
                    }
                }
        }

        // cross-cg reduce via LDS scratch (reuse zhi), then write per-slice partials
        __syncthreads();
        float* dsc = reinterpret_cast<float*>(zhi);          // [4][128]
        int*   ksc = reinterpret_cast<int*>(zhi) + 512;
        float* ssc = reinterpret_cast<float*>(zhi) + 1024;
        if (l15 == 0) {
            #pragma unroll
            for (int rf = 0; rf < 4; ++rf)
                #pragma unroll
                for (int reg = 0; reg < 4; ++reg) {
                    int rrow = rg * 64 + rf * 16 + lhi * 4 + reg;
                    dsc[cg * 128 + rrow] = bestd[rf][reg];
                    ksc[cg * 128 + rrow] = bestk[rf][reg];
                    ssc[cg * 128 + rrow] = secd[rf][reg];
                }
        }
        __syncthreads();
        if (tid < 128) {
            float bd = dsc[tid];
            int   bk = ksc[tid];
            float sd = ssc[tid];
            #pragma unroll
            for (int c = 1; c < 4; ++c) {
                float od = dsc[c * 128 + tid];
                int   ok = ksc[c * 128 + tid];
                float os = ssc[c * 128 + tid];
                float hi = fmaxf(bd, od);
                sd = fminf(fminf(sd, os), hi);
                if (od < bd || (od == bd && ok < bk)) { bd = od; bk = ok; }
            }
            int row = rowBase + tid;
            pd[row * NSLICE + slice] = bd;
            ps[row * NSLICE + slice] = sd;
            pk[row * NSLICE + slice] = bk;
        }
    }
}

// merge 8 slices per row: lexicographic best + merged second-best margin
__global__ __launch_bounds__(256) void slice_reduce_kernel(
    const float* __restrict__ pd, const float* __restrict__ ps, const int* __restrict__ pk,
    int* __restrict__ codes, float* __restrict__ codes_f,
    int* __restrict__ cnt, int* __restrict__ list)
{
    int row = blockIdx.x * 256 + threadIdx.x;
    float bd = FLT_MAX, sd = FLT_MAX;
    int bk = 0;
    #pragma unroll
    for (int s = 0; s < NSLICE; ++s) {
        float d  = pd[row * NSLICE + s];
        int   k  = pk[row * NSLICE + s];
        float s2 = ps[row * NSLICE + s];
        float hi = fmaxf(bd, d);
        sd = fminf(fminf(sd, s2), hi);
        if (d < bd || (d == bd && k < bk)) { bd = d; bk = k; }
    }
    codes[row]   = bk;
    codes_f[row] = (float)bk;
    if ((sd - bd) < TAU) {
        int idx = atomicAdd(cnt, 1);
        list[idx] = row;
    }
}

// ---------------- round-4 fallback kernel (proven) ----------------
template <bool PRECONV, bool REFINE>
__global__ __launch_bounds__(512, 1) void vq_mfma_kernel(
    const float* __restrict__ z, const float* __restrict__ cb,
    const _Float16* __restrict__ bhip, const _Float16* __restrict__ blop,
    const float* __restrict__ znorm, const float* __restrict__ cbnorm,
    int* __restrict__ codes, float* __restrict__ codes_f,
    int* __restrict__ cnt, int* __restrict__ list)
{
    __shared__ _Float16 zhi[BM * DD];
    __shared__ _Float16 zlo[BM * DD];
    const int tid  = threadIdx.x;
    const int lane = tid & 63;
    const int w    = tid >> 6;
    const int rg   = w >> 2;
    const int cg   = w & 3;
    const int l15  = lane & 15;
    const int lhi  = lane >> 4;
    const int rowBase = blockIdx.x * BM;

    #pragma unroll
    for (int i = 0; i < 16; ++i) {
        int gid = i * 512 + tid;
        int r   = gid >> 6;
        int c4  = gid & 63;
        float4 v = ((const float4*)z)[(size_t)(rowBase + r) * D4 + c4];
        _Float16 h0 = (_Float16)v.x, h1 = (_Float16)v.y,
                 h2 = (_Float16)v.z, h3 = (_Float16)v.w;
        _Float16 e0 = (_Float16)((v.x - (float)h0) * 2048.f);
        _Float16 e1 = (_Float16)((v.y - (float)h1) * 2048.f);
        _Float16 e2 = (_Float16)((v.z - (float)h2) * 2048.f);
        _Float16 e3 = (_Float16)((v.w - (float)h3) * 2048.f);
        int g = c4 >> 1;
        int byteOff = r * 512 + (((g ^ (r & 7))) << 4) + ((c4 & 1) << 3);
        *reinterpret_cast<half4*>(reinterpret_cast<char*>(zhi) + byteOff) = half4{h0, h1, h2, h3};
        *reinterpret_cast<half4*>(reinterpret_cast<char*>(zlo) + byteOff) = half4{e0, e1, e2, e3};
    }
    int rowA[4];
    #pragma unroll
    for (int rf = 0; rf < 4; ++rf) rowA[rf] = rg * 64 + rf * 16 + l15;
    float zn[4][4];
    #pragma unroll
    for (int rf = 0; rf < 4; ++rf)
        #pragma unroll
        for (int reg = 0; reg < 4; ++reg)
            zn[rf][reg] = znorm[rowBase + rg * 64 + rf * 16 + lhi * 4 + reg];
    float bestd[4][4], secd[4][4];
    int   bestk[4][4];
    #pragma unroll
    for (int rf = 0; rf < 4; ++rf)
        #pragma unroll
        for (int reg = 0; reg < 4; ++reg) {
            bestd[rf][reg] = FLT_MAX; secd[rf][reg] = FLT_MAX; bestk[rf][reg] = 0;
        }
    __syncthreads();
    for (int kt = 0; kt < KK / 256; ++kt) {
        floatx4 accH[4][4], accM[4][4];
        #pragma unroll
        for (int rf = 0; rf < 4; ++rf)
            #pragma unroll
            for (int cf = 0; cf < 4; ++cf) {
                accH[rf][cf] = floatx4{0.f, 0.f, 0.f, 0.f};
                accM[rf][cf] = floatx4{0.f, 0.f, 0.f, 0.f};
            }
        const int codeBase = kt * 256 + cg * 64 + l15;
        for (int dc = 0; dc < 8; ++dc) {
            half8 bhi_f[4], blo_f[4];
            #pragma unroll
            for (int cf = 0; cf < 4; ++cf) {
                if (PRECONV) {
                    size_t off = (size_t)(codeBase + 16 * cf) * DD + dc * 32 + lhi * 8;
                    bhi_f[cf] = *reinterpret_cast<const half8*>(bhip + off);
                    blo_f[cf] = *reinterpret_cast<const half8*>(blop + off);
                } else {
                    const float4* p = (const float4*)(cb + (size_t)(codeBase + 16 * cf) * DD + dc * 32 + lhi * 8);
                    float4 u0 = p[0];
                    float4 u1 = p[1];
                    float uv[8] = {u0.x, u0.y, u0.z, u0.w, u1.x, u1.y, u1.z, u1.w};
                    half8 bh, bl;
                    #pragma unroll
                    for (int jj = 0; jj < 8; ++jj) {
                        float t = uv[jj] * 16.f;
                        _Float16 h = (_Float16)t;
                        bh[jj] = h;
                        bl[jj] = (_Float16)((t - (float)h) * 2048.f);
                    }
                    bhi_f[cf] = bh; blo_f[cf] = bl;
                }
            }
            #pragma unroll
            for (int rf = 0; rf < 4; ++rf) {
                int g = dc * 4 + lhi;
                int off = rowA[rf] * 512 + ((g ^ (rowA[rf] & 7)) << 4);
                half8 ahi = *reinterpret_cast<const half8*>(reinterpret_cast<const char*>(zhi) + off);
                half8 alo = *reinterpret_cast<const half8*>(reinterpret_cast<const char*>(zlo) + off);
                #pragma unroll
                for (int cf = 0; cf < 4; ++cf) {
                    accH[rf][cf] = __builtin_amdgcn_mfma_f32_16x16x32_f16(ahi, bhi_f[cf], accH[rf][cf], 0, 0, 0);
                    accM[rf][cf] = __builtin_amdgcn_mfma_f32_16x16x32_f16(alo, bhi_f[cf], accM[rf][cf], 0, 0, 0);
                    accM[rf][cf] = __builtin_amdgcn_mfma_f32_16x16x32_f16(ahi, blo_f[cf], accM[rf][cf], 0, 0, 0);
                }
            }
        }
        #pragma unroll
        for (int cf = 0; cf < 4; ++cf) {
            int k = codeBase + 16 * cf;
            float cn = cbnorm[k];
            #pragma unroll
            for (int rf = 0; rf < 4; ++rf)
                #pragma unroll
                for (int reg = 0; reg < 4; ++reg) {
                    float dot16 = fmaf(accM[rf][cf][reg], 0x1p-11f, accH[rf][cf][reg]);
                    float dist  = fmaf(-0.125f, dot16, zn[rf][reg]) + cn;
                    if (dist < bestd[rf][reg]) {
                        secd[rf][reg] = bestd[rf][reg];
                        bestd[rf][reg] = dist; bestk[rf][reg] = k;
                    } else {
                        secd[rf][reg] = fminf(secd[rf][reg], dist);
                    }
                }
        }
    }
    #pragma unroll
    for (int off = 1; off < 16; off <<= 1) {
        #pragma unroll
        for (int rf = 0; rf < 4; ++rf)
            #pragma unroll
            for (int reg = 0; reg < 4; ++reg) {
                float od = __shfl_xor(bestd[rf][reg], off);
                int   ok = __shfl_xor(bestk[rf][reg], off);
                float os = __shfl_xor(secd[rf][reg], off);
                float hi = fmaxf(bestd[rf][reg], od);
                secd[rf][reg] = fminf(fminf(secd[rf][reg], os), hi);
                if (od < bestd[rf][reg] || (od == bestd[rf][reg] && ok < bestk[rf][reg])) {
                    bestd[rf][reg] = od; bestk[rf][reg] = ok;
                }
            }
    }
    __syncthreads();
    float* dsc = reinterpret_cast<float*>(zhi);
    int*   ksc = reinterpret_cast<int*>(zhi) + 512;
    float* ssc = reinterpret_cast<float*>(zhi) + 1024;
    if (l15 == 0) {
        #pragma unroll
        for (int rf = 0; rf < 4; ++rf)
            #pragma unroll
            for (int reg = 0; reg < 4; ++reg) {
                int rrow = rg * 64 + rf * 16 + lhi * 4 + reg;
                dsc[cg * 128 + rrow] = bestd[rf][reg];
                ksc[cg * 128 + rrow] = bestk[rf][reg];
                ssc[cg * 128 + rrow] = secd[rf][reg];
            }
    }
    __syncthreads();
    if (tid < 128) {
        float bd = dsc[tid];
        int   bk = ksc[tid];
        float sd = ssc[tid];
        #pragma unroll
        for (int c = 1; c < 4; ++c) {
            float od = dsc[c * 128 + tid];
            int   ok = ksc[c * 128 + tid];
            float os = ssc[c * 128 + tid];
            float hi = fmaxf(bd, od);
            sd = fminf(fminf(sd, os), hi);
            if (od < bd || (od == bd && ok < bk)) { bd = od; bk = ok; }
        }
        int row = rowBase + tid;
        codes[row]   = bk;
        codes_f[row] = (float)bk;
        if (REFINE && (sd - bd) < TAU) {
            int idx = atomicAdd(cnt, 1);
            list[idx] = row;
        }
    }
}

// Full fp32 re-argmin for flagged near-tie rows.
__global__ __launch_bounds__(256) void refine_kernel(
    const float* __restrict__ z, const float* __restrict__ cb,
    const float* __restrict__ znorm, const float* __restrict__ cbnorm,
    const int* __restrict__ cnt, const int* __restrict__ list,
    int* __restrict__ codes, float* __restrict__ codes_f)
{
    __shared__ float zrow[DD];
    __shared__ float dred[4];
    __shared__ int   kred[4];
    const int tid = threadIdx.x;
    const int lane = tid & 63;
    const int wv = tid >> 6;
    const int n = *cnt;
    for (int i = blockIdx.x; i < n; i += gridDim.x) {
        const int row = list[i];
        if (tid < 64) ((float4*)zrow)[tid] = ((const float4*)z)[(size_t)row * D4 + tid];
        const float zn = znorm[row];
        __syncthreads();
        float bd = FLT_MAX;
        int   bk = 0;
        for (int k = tid; k < KK; k += 256) {
            const float4* crow = (const float4*)cb + (size_t)k * D4;
            float acc = 0.f;
            #pragma unroll 8
            for (int d4 = 0; d4 < D4; ++d4) {
                float4 c = crow[d4];
                float4 zv = ((const float4*)zrow)[d4];
                acc = fmaf(zv.x, c.x, acc);
                acc = fmaf(zv.y, c.y, acc);
                acc = fmaf(zv.z, c.z, acc);
                acc = fmaf(zv.w, c.w, acc);
            }
            float dist = fmaf(-2.f, acc, zn) + cbnorm[k];
            if (dist < bd) { bd = dist; bk = k; }
        }
        #pragma unroll
        for (int off = 1; off < 64; off <<= 1) {
            float od = __shfl_xor(bd, off);
            int   ok = __shfl_xor(bk, off);
            if (od < bd || (od == bd && ok < bk)) { bd = od; bk = ok; }
        }
        if (lane == 0) { dred[wv] = bd; kred[wv] = bk; }
        __syncthreads();
        if (tid == 0) {
            #pragma unroll
            for (int c = 1; c < 4; ++c) {
                if (dred[c] < bd || (dred[c] == bd && kred[c] < bk)) { bd = dred[c]; bk = kred[c]; }
            }
            codes[row]   = bk;
            codes_f[row] = (float)bk;
        }
        __syncthreads();
    }
}

__global__ __launch_bounds__(256) void gather_loss_kernel(
    const float* __restrict__ z, const float* __restrict__ cb,
    const int* __restrict__ codes, float* __restrict__ zq_out,
    float* __restrict__ partials)
{
    __shared__ float red[4];
    int tid = threadIdx.x;
    size_t e4 = (size_t)blockIdx.x * 256 + tid;
    int row = (int)(e4 >> 6);
    int d4  = (int)(e4 & 63);
    int code = codes[row];
    float4 q  = ((const float4*)cb)[(size_t)code * D4 + d4];
    float4 zv = ((const float4*)z)[e4];
    float dx = q.x - zv.x, dy = q.y - zv.y, dz = q.z - zv.z, dw = q.w - zv.w;
    float4 o;
    o.x = zv.x + dx; o.y = zv.y + dy; o.z = zv.z + dz; o.w = zv.w + dw;
    ((float4*)zq_out)[e4] = o;
    float s = dx*dx + dy*dy + dz*dz + dw*dw;
    #pragma unroll
    for (int off = 1; off < 64; off <<= 1) s += __shfl_xor(s, off);
    if ((tid & 63) == 0) red[tid >> 6] = s;
    __syncthreads();
    if (tid == 0) partials[blockIdx.x] = ((red[0] + red[1]) + red[2]) + red[3];
}

__global__ __launch_bounds__(256) void final_loss_kernel(
    const float* __restrict__ partials, float* __restrict__ out_loss)
{
    __shared__ float red[4];
    int tid = threadIdx.x;
    float s = 0.f;
    #pragma unroll 4
    for (int i = 0; i < 32; ++i) s += partials[tid * 32 + i];
    #pragma unroll
    for (int off = 1; off < 64; off <<= 1) s += __shfl_xor(s, off);
    if ((tid & 63) == 0) red[tid >> 6] = s;
    __syncthreads();
    if (tid == 0) {
        float tot = ((red[0] + red[1]) + red[2]) + red[3];
        out_loss[0] = 0.5f * (tot / (float)NELEM);
    }
}

extern "C" void kernel_launch(void* const* d_in, const int* in_sizes, int n_in,
                              void* d_out, int out_size, void* d_ws, size_t ws_size,
                              hipStream_t stream) {
    const float* z  = (const float*)d_in[0];
    const float* cb = (const float*)d_in[1];
    float* out      = (float*)d_out;
    float* zq_out   = out;
    float* loss_out = out + NELEM;
    float* codes_f  = out + NELEM + 1;

    char* wsb       = (char*)d_ws;
    float* znorm    = (float*)(wsb + 0);
    float* cbnorm   = (float*)(wsb + 131072);
    int*   codes    = (int*)(wsb + 163840);
    float* partials = (float*)(wsb + 294912);
    int*   cnt      = (int*)(wsb + 327680);
    int*   list     = (int*)(wsb + 327696);

    norms_kernel<<<10240, 256, 0, stream>>>(z, cb, znorm, cbnorm);

    if (ws_size >= (size_t)WS_SLICED_BYTES) {
        float* pd     = (float*)(wsb + 460800);
        float* ps     = (float*)(wsb + 1509376);
        int*   pk     = (int*)(wsb + 2557952);
        _Float16* bhi = (_Float16*)(wsb + 3606528);
        _Float16* blo = (_Float16*)(wsb + 7800832);
        hipMemsetAsync(cnt, 0, sizeof(int), stream);
        preconv_kernel<<<2048, 256, 0, stream>>>(cb, bhi, blo);
        vq_sliced_kernel<<<NTILES, 512, 0, stream>>>(z, bhi, blo, znorm, cbnorm, pd, ps, pk);
        slice_reduce_kernel<<<128, 256, 0, stream>>>(pd, ps, pk, codes, codes_f, cnt, list);
        refine_kernel<<<256, 256, 0, stream>>>(z, cb, znorm, cbnorm, cnt, list, codes, codes_f);
    } else {
        _Float16* bhi = (_Float16*)(wsb + 460800);
        _Float16* blo = (_Float16*)(wsb + 4655104);
        const bool preconv = ws_size >= (size_t)WS_R4_FULL_BYTES;
        const bool refine  = ws_size >= (size_t)WS_R4_REFINE_BYTES;
        if (refine) hipMemsetAsync(cnt, 0, sizeof(int), stream);
        if (preconv) preconv_kernel<<<2048, 256, 0, stream>>>(cb, bhi, blo);
        if (preconv && refine)
            vq_mfma_kernel<true, true><<<NROWS / BM, 512, 0, stream>>>(z, cb, bhi, blo, znorm, cbnorm, codes, codes_f, cnt, list);
        else if (preconv)
            vq_mfma_kernel<true, false><<<NROWS / BM, 512, 0, stream>>>(z, cb, bhi, blo, znorm, cbnorm, codes, codes_f, cnt, list);
        else if (refine)
            vq_mfma_kernel<false, true><<<NROWS / BM, 512, 0, stream>>>(z, cb, bhi, blo, znorm, cbnorm, codes, codes_f, cnt, list);
        else
            vq_mfma_kernel<false, false><<<NROWS / BM, 512, 0, stream>>>(z, cb, bhi, blo, znorm, cbnorm, codes, codes_f, cnt, list);
        if (refine)
            refine_kernel<<<256, 256, 0, stream>>>(z, cb, znorm, cbnorm, cnt, list, codes, codes_f);
    }

    gather_loss_kernel<<<8192, 256, 0, stream>>>(z, cb, codes, zq_out, partials);
    final_loss_kernel<<<1, 256, 0, stream>>>(partials, loss_out);
}